// Round 1
// 149.759 us; speedup vs baseline: 1.0001x; 1.0001x over previous
//
#include <hip/hip_runtime.h>
#include <math.h>

// R1: occupancy attack. Old: 128T/block, 32KB LDS -> 5 blk/CU = 31% occ cap,
// 2x vmcnt(0) drains + 2x __syncthreads per block => latency-bound at 19.5% occ.
// New: 64T (1 wave) / 16 batches / 4 lanes-per-batch, two 4032B LDS buffers
// (8064 B/block -> 20 blk/CU = 62.5% occ cap), both tensors' DMA issued
// back-to-back, ONE vmcnt(0), ZERO barriers (single-wave lockstep).
#define NPTS 21
#define FLB  63               // floats per batch per tensor
#define BPB  16               // batches per block
#define THREADS 64            // one wave per block
#define TVEC (BPB * FLB / 4)  // 252 float4 per tensor chunk
#define FULLR (TVEC / THREADS)   // 3
#define TAILL (TVEC % THREADS)   // 60

// direct global->LDS DMA, 16B per lane; lds ptr must be wave-uniform (HW adds lane*16)
__device__ __forceinline__ void async_cp16(const float* g, float* l) {
    __builtin_amdgcn_global_load_lds(
        (__attribute__((address_space(1))) void*)g,
        (__attribute__((address_space(3))) void*)l,
        16, 0, 0);
}

__global__ __launch_bounds__(THREADS, 5)   // 5 waves/EU -> VGPR budget 102
void pa_mpjpe(const float* __restrict__ pred,
              const float* __restrict__ targ,
              float* __restrict__ ws,
              int B)
{
    __shared__ __align__(16) float ly[BPB * FLB];   // pred chunk, 4032 B
    __shared__ __align__(16) float lx[BPB * FLB];   // targ chunk, 4032 B

    const int tid = threadIdx.x;
    const int b   = tid & (BPB - 1);   // batch within block
    const int sub = tid >> 4;          // 0..3 : point-slice within batch
    const int b0  = blockIdx.x * BPB;

    // ---- stage BOTH tensors, one drain, no barriers ----
    {
        const float* gp = pred + (size_t)b0 * FLB;
        const float* gt = targ + (size_t)b0 * FLB;
        #pragma unroll
        for (int j = 0; j < FULLR; ++j)
            async_cp16(gp + 4 * (j * THREADS + tid), ly + 4 * (j * THREADS));
        if (tid < TAILL)
            async_cp16(gp + 4 * (FULLR * THREADS + tid), ly + 4 * (FULLR * THREADS));
        #pragma unroll
        for (int j = 0; j < FULLR; ++j)
            async_cp16(gt + 4 * (j * THREADS + tid), lx + 4 * (j * THREADS));
        if (tid < TAILL)
            async_cp16(gt + 4 * (FULLR * THREADS + tid), lx + 4 * (FULLR * THREADS));
    }
    __builtin_amdgcn_s_waitcnt(0x0F70);   // vmcnt(0); expcnt/lgkmcnt ignored

    // ---- pass 1: per-lane partial moments over points n = sub + 4k ----
    float py0[6], py1[6], py2[6];                     // this lane's pred points
    float sy0=0.f, sy1=0.f, sy2=0.f, syy=0.f;
    float sx0=0.f, sx1=0.f, sx2=0.f;
    float m00=0,m01=0,m02=0, m10=0,m11=0,m12=0, m20=0,m21=0,m22=0;
    const int base = b * FLB;
    #pragma unroll
    for (int k = 0; k < 6; ++k) {
        const int n = sub + 4 * k;
        if (n < NPTS) {
            const int o = base + 3 * n;
            float a = ly[o+0], e = ly[o+1], c = ly[o+2];   // pred (Y)
            float u = lx[o+0], v = lx[o+1], w = lx[o+2];   // targ (X)
            py0[k] = a; py1[k] = e; py2[k] = c;
            sy0 += a; sy1 += e; sy2 += c;
            syy = fmaf(a, a, fmaf(e, e, fmaf(c, c, syy)));
            sx0 += u; sx1 += v; sx2 += w;
            m00 = fmaf(u,a,m00); m01 = fmaf(u,e,m01); m02 = fmaf(u,c,m02);
            m10 = fmaf(v,a,m10); m11 = fmaf(v,e,m11); m12 = fmaf(v,c,m12);
            m20 = fmaf(w,a,m20); m21 = fmaf(w,e,m21); m22 = fmaf(w,c,m22);
        } else {
            py0[k] = 0.f; py1[k] = 0.f; py2[k] = 0.f;
        }
    }

    // ---- combine the 4 lanes of each batch (xor 16 then 32 flips 'sub') ----
    #define COMB(v) { v += __shfl_xor(v, 16, 64); v += __shfl_xor(v, 32, 64); }
    COMB(sy0) COMB(sy1) COMB(sy2) COMB(syy)
    COMB(sx0) COMB(sx1) COMB(sx2)
    COMB(m00) COMB(m01) COMB(m02)
    COMB(m10) COMB(m11) COMB(m12)
    COMB(m20) COMB(m21) COMB(m22)
    #undef COMB

    const float invN = 1.0f / (float)NPTS;
    float mux0 = sx0*invN, mux1 = sx1*invN, mux2 = sx2*invN;
    float muy0 = sy0*invN, muy1 = sy1*invN, muy2 = sy2*invN;
    float ny2  = syy - (sy0*sy0 + sy1*sy1 + sy2*sy2) * invN;   // ||Y0||_F^2
    // centered cross-cov (rows: targ dims i, cols: pred dims j)
    float c00 = m00 - sx0*sy0*invN, c01 = m01 - sx0*sy1*invN, c02 = m02 - sx0*sy2*invN;
    float c10 = m10 - sx1*sy0*invN, c11 = m11 - sx1*sy1*invN, c12 = m12 - sx1*sy2*invN;
    float c20 = m20 - sx2*sy0*invN, c21 = m21 - sx2*sy1*invN, c22 = m22 - sx2*sy2*invN;

    // ---- orthogonal polar factor of A = Mc^T via det-scaled Newton ----
    // (redundant on all 4 lanes of a batch; VALU is not the bottleneck)
    float q00=c00, q01=c10, q02=c20,
          q10=c01, q11=c11, q12=c21,
          q20=c02, q21=c12, q22=c22;
    #pragma unroll
    for (int it = 0; it < 8; ++it) {
        float C00 = q11*q22 - q12*q21;
        float C01 = q12*q20 - q10*q22;
        float C02 = q10*q21 - q11*q20;
        float C10 = q02*q21 - q01*q22;
        float C11 = q00*q22 - q02*q20;
        float C12 = q01*q20 - q00*q21;
        float C20 = q01*q12 - q02*q11;
        float C21 = q02*q10 - q00*q12;
        float C22 = q00*q11 - q01*q10;
        float det = q00*C00 + q01*C01 + q02*C02;
        float ad  = fmaxf(fabsf(det), 1e-30f);
        float sdet = copysignf(ad, det);
        float g  = __expf(0.333333333f * __logf(ad));   // |det|^{1/3}
        float ha = 0.5f / g;                            // 0.5 * gamma
        float hb = 0.5f * g / sdet;                     // 0.5 * gamma^{-1} / det
        q00 = ha*q00 + hb*C00; q01 = ha*q01 + hb*C01; q02 = ha*q02 + hb*C02;
        q10 = ha*q10 + hb*C10; q11 = ha*q11 + hb*C11; q12 = ha*q12 + hb*C12;
        q20 = ha*q20 + hb*C20; q21 = ha*q21 + hb*C21; q22 = ha*q22 + hb*C22;
    }

    // tr(P) = <Q, A>_F with A = Mc^T (sum of singular values of Mc)
    float trP = q00*c00 + q01*c10 + q02*c20
              + q10*c01 + q11*c11 + q12*c21
              + q20*c02 + q21*c12 + q22*c22;
    float kk = trP / ny2;
    float r00=kk*q00, r01=kk*q01, r02=kk*q02;
    float r10=kk*q10, r11=kk*q11, r12=kk*q12;
    float r20=kk*q20, r21=kk*q21, r22=kk*q22;

    // ---- pass 2: per-joint error (targ re-read from LDS, pred from regs) ----
    float errsum = 0.0f;
    #pragma unroll
    for (int k = 0; k < 6; ++k) {
        const int n = sub + 4 * k;
        if (n < NPTS) {
            const int o = base + 3 * n;
            float xa = lx[o+0], xb = lx[o+1], xc = lx[o+2];
            float u = py0[k] - muy0, v = py1[k] - muy1, w = py2[k] - muy2;
            float z0 = fmaf(u, r00, fmaf(v, r10, fmaf(w, r20, mux0))) - xa;
            float z1 = fmaf(u, r01, fmaf(v, r11, fmaf(w, r21, mux1))) - xb;
            float z2 = fmaf(u, r02, fmaf(v, r12, fmaf(w, r22, mux2))) - xc;
            errsum += sqrtf(fmaf(z0, z0, fmaf(z1, z1, z2*z2)));
        }
    }

    // ---- full-wave reduce (covers all 16 batches) -> one store per block ----
    #pragma unroll
    for (int off = 32; off > 0; off >>= 1) errsum += __shfl_down(errsum, off, 64);
    if (tid == 0) ws[blockIdx.x] = errsum;
}

// single block: reduce the per-block partials, write the final mean
__global__ __launch_bounds__(256)
void pa_reduce(const float* __restrict__ ws, float* __restrict__ out,
               int nblk, float inv_total)
{
    __shared__ float sw[4];
    float s = 0.0f;
    const float4* w4 = (const float4*)ws;
    const int n4 = nblk >> 2;                  // nblk divisible by 4
    for (int i = threadIdx.x; i < n4; i += 256) {
        float4 v = w4[i];
        s += (v.x + v.y) + (v.z + v.w);
    }
    #pragma unroll
    for (int off = 32; off > 0; off >>= 1) s += __shfl_down(s, off, 64);
    if ((threadIdx.x & 63) == 0) sw[threadIdx.x >> 6] = s;
    __syncthreads();
    if (threadIdx.x == 0)
        out[0] = (sw[0] + sw[1] + sw[2] + sw[3]) * inv_total;
}

extern "C" void kernel_launch(void* const* d_in, const int* in_sizes, int n_in,
                              void* d_out, int out_size, void* d_ws, size_t ws_size,
                              hipStream_t stream)
{
    const float* pred = (const float*)d_in[0];   // pred_kp3d   [B,21,3] f32
    const float* targ = (const float*)d_in[1];   // target_kp3d [B,21,3] f32
    float* out = (float*)d_out;
    float* ws  = (float*)d_ws;

    int B = in_sizes[0] / FLB;                   // 262144 (divisible by BPB)
    int grid = (B + BPB - 1) / BPB;              // 16384
    float inv_total = 1.0f / ((float)B * (float)NPTS);

    pa_mpjpe<<<grid, THREADS, 0, stream>>>(pred, targ, ws, B);
    pa_reduce<<<1, 256, 0, stream>>>(ws, out, grid, inv_total);
}

// Round 2
// 149.013 us; speedup vs baseline: 1.0051x; 1.0050x over previous
//
#include <hip/hip_runtime.h>
#include <math.h>

// R2: VALU-issue + residency attack.
// R1 post-mortem: VALUBusy ~60% (28us of issue) vs ~10-15us memory floor
// (FETCH=66MB, half of input -- L3 serves the rest). Occupancy stuck at 36%
// vs 62.5% LDS cap with 1-wave blocks => suspect per-CU workgroup-slot limit.
// Fix 1: 256T blocks = 4 INDEPENDENT waves, private LDS slices, zero barriers.
//        32256 B/block -> 5 blocks/CU = 20 waves/CU (62.5% cap), 4096 blocks.
// Fix 2: Newton 8 -> 6 iters (det-scaled Newton is quadratic; ~17% VALU cut).
#define NPTS 21
#define FLB  63               // floats per batch per tensor
#define BPW  16               // batches per wave
#define WPB  4                // waves per block
#define BPB  (BPW * WPB)      // 64 batches per block
#define THREADS (64 * WPB)    // 256
#define TVEC (BPW * FLB / 4)  // 252 float4 per tensor per wave
#define FULLR (TVEC / 64)     // 3
#define TAILL (TVEC % 64)     // 60

// direct global->LDS DMA, 16B per lane; lds ptr must be wave-uniform (HW adds lane*16)
__device__ __forceinline__ void async_cp16(const float* g, float* l) {
    __builtin_amdgcn_global_load_lds(
        (__attribute__((address_space(1))) void*)g,
        (__attribute__((address_space(3))) void*)l,
        16, 0, 0);
}

__global__ __launch_bounds__(THREADS, 5)   // 5 waves/EU -> 5 blocks/CU, VGPR cap 102
void pa_mpjpe(const float* __restrict__ pred,
              const float* __restrict__ targ,
              float* __restrict__ ws,
              int B)
{
    // per-wave private slices: no inter-wave sharing, no barriers anywhere
    __shared__ __align__(16) float ly[WPB][BPW * FLB];   // pred, 4032 B/wave
    __shared__ __align__(16) float lx[WPB][BPW * FLB];   // targ, 4032 B/wave

    const int tid  = threadIdx.x;
    const int w    = tid >> 6;          // wave id, uniform per wave
    const int lane = tid & 63;
    const int b    = lane & (BPW - 1);  // batch within wave
    const int sub  = lane >> 4;         // 0..3 : point-slice within batch
    const int bw0  = blockIdx.x * BPB + w * BPW;   // first batch of this wave

    // ---- stage BOTH tensors for this wave, one drain, no barriers ----
    {
        const float* gp = pred + (size_t)bw0 * FLB;
        const float* gt = targ + (size_t)bw0 * FLB;
        #pragma unroll
        for (int j = 0; j < FULLR; ++j)
            async_cp16(gp + 4 * (j * 64 + lane), &ly[w][4 * (j * 64)]);
        if (lane < TAILL)
            async_cp16(gp + 4 * (FULLR * 64 + lane), &ly[w][4 * (FULLR * 64)]);
        #pragma unroll
        for (int j = 0; j < FULLR; ++j)
            async_cp16(gt + 4 * (j * 64 + lane), &lx[w][4 * (j * 64)]);
        if (lane < TAILL)
            async_cp16(gt + 4 * (FULLR * 64 + lane), &lx[w][4 * (FULLR * 64)]);
    }
    __builtin_amdgcn_s_waitcnt(0x0F70);   // vmcnt(0); expcnt/lgkmcnt ignored

    // ---- pass 1: per-lane partial moments over points n = sub + 4k ----
    float py0[6], py1[6], py2[6];                     // this lane's pred points
    float sy0=0.f, sy1=0.f, sy2=0.f, syy=0.f;
    float sx0=0.f, sx1=0.f, sx2=0.f;
    float m00=0,m01=0,m02=0, m10=0,m11=0,m12=0, m20=0,m21=0,m22=0;
    const int base = b * FLB;
    #pragma unroll
    for (int k = 0; k < 6; ++k) {
        const int n = sub + 4 * k;
        if (n < NPTS) {
            const int o = base + 3 * n;
            float a = ly[w][o+0], e = ly[w][o+1], c = ly[w][o+2];   // pred (Y)
            float u = lx[w][o+0], v = lx[w][o+1], x2 = lx[w][o+2];  // targ (X)
            py0[k] = a; py1[k] = e; py2[k] = c;
            sy0 += a; sy1 += e; sy2 += c;
            syy = fmaf(a, a, fmaf(e, e, fmaf(c, c, syy)));
            sx0 += u; sx1 += v; sx2 += x2;
            m00 = fmaf(u,a,m00); m01 = fmaf(u,e,m01); m02 = fmaf(u,c,m02);
            m10 = fmaf(v,a,m10); m11 = fmaf(v,e,m11); m12 = fmaf(v,c,m12);
            m20 = fmaf(x2,a,m20); m21 = fmaf(x2,e,m21); m22 = fmaf(x2,c,m22);
        } else {
            py0[k] = 0.f; py1[k] = 0.f; py2[k] = 0.f;
        }
    }

    // ---- combine the 4 lanes of each batch (xor 16 then 32 flips 'sub') ----
    #define COMB(v) { v += __shfl_xor(v, 16, 64); v += __shfl_xor(v, 32, 64); }
    COMB(sy0) COMB(sy1) COMB(sy2) COMB(syy)
    COMB(sx0) COMB(sx1) COMB(sx2)
    COMB(m00) COMB(m01) COMB(m02)
    COMB(m10) COMB(m11) COMB(m12)
    COMB(m20) COMB(m21) COMB(m22)
    #undef COMB

    const float invN = 1.0f / (float)NPTS;
    float mux0 = sx0*invN, mux1 = sx1*invN, mux2 = sx2*invN;
    float muy0 = sy0*invN, muy1 = sy1*invN, muy2 = sy2*invN;
    float ny2  = syy - (sy0*sy0 + sy1*sy1 + sy2*sy2) * invN;   // ||Y0||_F^2
    // centered cross-cov (rows: targ dims i, cols: pred dims j)
    float c00 = m00 - sx0*sy0*invN, c01 = m01 - sx0*sy1*invN, c02 = m02 - sx0*sy2*invN;
    float c10 = m10 - sx1*sy0*invN, c11 = m11 - sx1*sy1*invN, c12 = m12 - sx1*sy2*invN;
    float c20 = m20 - sx2*sy0*invN, c21 = m21 - sx2*sy1*invN, c22 = m22 - sx2*sy2*invN;

    // ---- orthogonal polar factor of A = Mc^T via det-scaled Newton ----
    // (still 4x redundant per batch; next lever if VALU remains dominant)
    float q00=c00, q01=c10, q02=c20,
          q10=c01, q11=c11, q12=c21,
          q20=c02, q21=c12, q22=c22;
    #pragma unroll
    for (int it = 0; it < 6; ++it) {
        float C00 = q11*q22 - q12*q21;
        float C01 = q12*q20 - q10*q22;
        float C02 = q10*q21 - q11*q20;
        float C10 = q02*q21 - q01*q22;
        float C11 = q00*q22 - q02*q20;
        float C12 = q01*q20 - q00*q21;
        float C20 = q01*q12 - q02*q11;
        float C21 = q02*q10 - q00*q12;
        float C22 = q00*q11 - q01*q10;
        float det = q00*C00 + q01*C01 + q02*C02;
        float ad  = fmaxf(fabsf(det), 1e-30f);
        float sdet = copysignf(ad, det);
        float g  = __expf(0.333333333f * __logf(ad));   // |det|^{1/3}
        float ha = 0.5f / g;                            // 0.5 * gamma
        float hb = 0.5f * g / sdet;                     // 0.5 * gamma^{-1} / det
        q00 = ha*q00 + hb*C00; q01 = ha*q01 + hb*C01; q02 = ha*q02 + hb*C02;
        q10 = ha*q10 + hb*C10; q11 = ha*q11 + hb*C11; q12 = ha*q12 + hb*C12;
        q20 = ha*q20 + hb*C20; q21 = ha*q21 + hb*C21; q22 = ha*q22 + hb*C22;
    }

    // tr(P) = <Q, A>_F with A = Mc^T (sum of singular values of Mc)
    float trP = q00*c00 + q01*c10 + q02*c20
              + q10*c01 + q11*c11 + q12*c21
              + q20*c02 + q21*c12 + q22*c22;
    float kk = trP / ny2;
    float r00=kk*q00, r01=kk*q01, r02=kk*q02;
    float r10=kk*q10, r11=kk*q11, r12=kk*q12;
    float r20=kk*q20, r21=kk*q21, r22=kk*q22;

    // ---- pass 2: per-joint error (targ re-read from LDS, pred from regs) ----
    float errsum = 0.0f;
    #pragma unroll
    for (int k = 0; k < 6; ++k) {
        const int n = sub + 4 * k;
        if (n < NPTS) {
            const int o = base + 3 * n;
            float xa = lx[w][o+0], xb = lx[w][o+1], xc = lx[w][o+2];
            float u = py0[k] - muy0, v = py1[k] - muy1, x2 = py2[k] - muy2;
            float z0 = fmaf(u, r00, fmaf(v, r10, fmaf(x2, r20, mux0))) - xa;
            float z1 = fmaf(u, r01, fmaf(v, r11, fmaf(x2, r21, mux1))) - xb;
            float z2 = fmaf(u, r02, fmaf(v, r12, fmaf(x2, r22, mux2))) - xc;
            errsum += sqrtf(fmaf(z0, z0, fmaf(z1, z1, z2*z2)));
        }
    }

    // ---- full-wave reduce -> one store per WAVE (no cross-wave traffic) ----
    #pragma unroll
    for (int off = 32; off > 0; off >>= 1) errsum += __shfl_down(errsum, off, 64);
    if (lane == 0) ws[blockIdx.x * WPB + w] = errsum;
}

// single block: reduce the per-wave partials, write the final mean
__global__ __launch_bounds__(256)
void pa_reduce(const float* __restrict__ ws, float* __restrict__ out,
               int nblk, float inv_total)
{
    __shared__ float sw[4];
    float s = 0.0f;
    const float4* w4 = (const float4*)ws;
    const int n4 = nblk >> 2;                  // nblk divisible by 4
    for (int i = threadIdx.x; i < n4; i += 256) {
        float4 v = w4[i];
        s += (v.x + v.y) + (v.z + v.w);
    }
    #pragma unroll
    for (int off = 32; off > 0; off >>= 1) s += __shfl_down(s, off, 64);
    if ((threadIdx.x & 63) == 0) sw[threadIdx.x >> 6] = s;
    __syncthreads();
    if (threadIdx.x == 0)
        out[0] = (sw[0] + sw[1] + sw[2] + sw[3]) * inv_total;
}

extern "C" void kernel_launch(void* const* d_in, const int* in_sizes, int n_in,
                              void* d_out, int out_size, void* d_ws, size_t ws_size,
                              hipStream_t stream)
{
    const float* pred = (const float*)d_in[0];   // pred_kp3d   [B,21,3] f32
    const float* targ = (const float*)d_in[1];   // target_kp3d [B,21,3] f32
    float* out = (float*)d_out;
    float* ws  = (float*)d_ws;

    int B = in_sizes[0] / FLB;                   // 262144 (divisible by BPB)
    int grid = (B + BPB - 1) / BPB;              // 4096 blocks, 4 waves each
    int npart = grid * WPB;                      // 16384 partials
    float inv_total = 1.0f / ((float)B * (float)NPTS);

    pa_mpjpe<<<grid, THREADS, 0, stream>>>(pred, targ, ws, B);
    pa_reduce<<<1, 256, 0, stream>>>(ws, out, npart, inv_total);
}

// Round 3
// 146.725 us; speedup vs baseline: 1.0208x; 1.0156x over previous
//
#include <hip/hip_runtime.h>
#include <math.h>

// R3: issue-per-batch attack. R2 falsified the workgroup-slot theory
// (occupancy pinned ~10 waves/CU regardless of block shape). VALUBusy ~57%
// at 48us vs ~12us memory floor => cut wave-instruction issue per batch.
// 16 -> 32 batches/wave (2 lanes/batch, even/odd points): Newton+mid+combine
// amortize over 2x batches, combine drops 2 shuffle levels -> 1.
// ~39 -> ~24 wave-ops/batch. LDS 16128 B/wave -> 10 blocks/CU cap = the
// measured residency plateau, so occupancy should be unaffected.
#define NPTS 21
#define FLB  63               // floats per batch per tensor
#define BPW  32               // batches per wave
#define THREADS 64            // one wave per block
#define TVEC (BPW * FLB / 4)  // 504 float4 per tensor chunk
#define FULLR (TVEC / 64)     // 7
#define TAILL (TVEC % 64)     // 56
#define KMAX 11               // points per lane (even lane-half: 11, odd: 10)

// direct global->LDS DMA, 16B per lane; lds ptr must be wave-uniform (HW adds lane*16)
__device__ __forceinline__ void async_cp16(const float* g, float* l) {
    __builtin_amdgcn_global_load_lds(
        (__attribute__((address_space(1))) void*)g,
        (__attribute__((address_space(3))) void*)l,
        16, 0, 0);
}

__global__ __launch_bounds__(THREADS, 3)   // 3 waves/EU min; LDS caps at 10 blocks/CU
void pa_mpjpe(const float* __restrict__ pred,
              const float* __restrict__ targ,
              float* __restrict__ ws,
              int B)
{
    __shared__ __align__(16) float ly[BPW * FLB];   // pred chunk, 8064 B
    __shared__ __align__(16) float lx[BPW * FLB];   // targ chunk, 8064 B

    const int lane = threadIdx.x & 63;
    const int b    = lane & (BPW - 1);        // batch within wave
    const int sub  = (lane >> 5) & 1;         // 0: even points, 1: odd points
    const int b0   = blockIdx.x * BPW;

    // ---- stage BOTH tensors, one drain, no barriers (single-wave block) ----
    {
        const float* gp = pred + (size_t)b0 * FLB;
        const float* gt = targ + (size_t)b0 * FLB;
        #pragma unroll
        for (int j = 0; j < FULLR; ++j)
            async_cp16(gp + 4 * (j * 64 + lane), ly + 4 * (j * 64));
        if (lane < TAILL)
            async_cp16(gp + 4 * (FULLR * 64 + lane), ly + 4 * (FULLR * 64));
        #pragma unroll
        for (int j = 0; j < FULLR; ++j)
            async_cp16(gt + 4 * (j * 64 + lane), lx + 4 * (j * 64));
        if (lane < TAILL)
            async_cp16(gt + 4 * (FULLR * 64 + lane), lx + 4 * (FULLR * 64));
    }
    __builtin_amdgcn_s_waitcnt(0x0F70);   // vmcnt(0); expcnt/lgkmcnt ignored

    // ---- pass 1: per-lane partial moments over points n = 2k + sub ----
    float py0[KMAX], py1[KMAX], py2[KMAX];            // this lane's pred points
    float sy0=0.f, sy1=0.f, sy2=0.f, syy=0.f;
    float sx0=0.f, sx1=0.f, sx2=0.f;
    float m00=0,m01=0,m02=0, m10=0,m11=0,m12=0, m20=0,m21=0,m22=0;
    const int base = b * FLB;
    #pragma unroll
    for (int k = 0; k < KMAX; ++k) {
        const int n = 2 * k + sub;
        if (n < NPTS) {                                // only k=10,sub=1 masked
            const int o = base + 3 * n;
            float a = ly[o+0], e = ly[o+1], c = ly[o+2];   // pred (Y)
            float u = lx[o+0], v = lx[o+1], x2 = lx[o+2];  // targ (X)
            py0[k] = a; py1[k] = e; py2[k] = c;
            sy0 += a; sy1 += e; sy2 += c;
            syy = fmaf(a, a, fmaf(e, e, fmaf(c, c, syy)));
            sx0 += u; sx1 += v; sx2 += x2;
            m00 = fmaf(u,a,m00); m01 = fmaf(u,e,m01); m02 = fmaf(u,c,m02);
            m10 = fmaf(v,a,m10); m11 = fmaf(v,e,m11); m12 = fmaf(v,c,m12);
            m20 = fmaf(x2,a,m20); m21 = fmaf(x2,e,m21); m22 = fmaf(x2,c,m22);
        } else {
            py0[k] = 0.f; py1[k] = 0.f; py2[k] = 0.f;
        }
    }

    // ---- combine the 2 lanes of each batch (xor 32 = permlane32 swap) ----
    #define COMB(v) { v += __shfl_xor(v, 32, 64); }
    COMB(sy0) COMB(sy1) COMB(sy2) COMB(syy)
    COMB(sx0) COMB(sx1) COMB(sx2)
    COMB(m00) COMB(m01) COMB(m02)
    COMB(m10) COMB(m11) COMB(m12)
    COMB(m20) COMB(m21) COMB(m22)
    #undef COMB

    const float invN = 1.0f / (float)NPTS;
    float mux0 = sx0*invN, mux1 = sx1*invN, mux2 = sx2*invN;
    float muy0 = sy0*invN, muy1 = sy1*invN, muy2 = sy2*invN;
    float ny2  = syy - (sy0*sy0 + sy1*sy1 + sy2*sy2) * invN;   // ||Y0||_F^2
    // centered cross-cov (rows: targ dims i, cols: pred dims j)
    float c00 = m00 - sx0*sy0*invN, c01 = m01 - sx0*sy1*invN, c02 = m02 - sx0*sy2*invN;
    float c10 = m10 - sx1*sy0*invN, c11 = m11 - sx1*sy1*invN, c12 = m12 - sx1*sy2*invN;
    float c20 = m20 - sx2*sy0*invN, c21 = m21 - sx2*sy1*invN, c22 = m22 - sx2*sy2*invN;

    // ---- orthogonal polar factor of A = Mc^T via det-scaled Newton ----
    float q00=c00, q01=c10, q02=c20,
          q10=c01, q11=c11, q12=c21,
          q20=c02, q21=c12, q22=c22;
    #pragma unroll
    for (int it = 0; it < 6; ++it) {
        float C00 = q11*q22 - q12*q21;
        float C01 = q12*q20 - q10*q22;
        float C02 = q10*q21 - q11*q20;
        float C10 = q02*q21 - q01*q22;
        float C11 = q00*q22 - q02*q20;
        float C12 = q01*q20 - q00*q21;
        float C20 = q01*q12 - q02*q11;
        float C21 = q02*q10 - q00*q12;
        float C22 = q00*q11 - q01*q10;
        float det = q00*C00 + q01*C01 + q02*C02;
        float ad  = fmaxf(fabsf(det), 1e-30f);
        float sdet = copysignf(ad, det);
        float g  = __expf(0.333333333f * __logf(ad));   // |det|^{1/3}
        float ha = 0.5f / g;                            // 0.5 * gamma
        float hb = 0.5f * g / sdet;                     // 0.5 * gamma^{-1} / det
        q00 = ha*q00 + hb*C00; q01 = ha*q01 + hb*C01; q02 = ha*q02 + hb*C02;
        q10 = ha*q10 + hb*C10; q11 = ha*q11 + hb*C11; q12 = ha*q12 + hb*C12;
        q20 = ha*q20 + hb*C20; q21 = ha*q21 + hb*C21; q22 = ha*q22 + hb*C22;
    }

    // tr(P) = <Q, A>_F with A = Mc^T (sum of singular values of Mc)
    float trP = q00*c00 + q01*c10 + q02*c20
              + q10*c01 + q11*c11 + q12*c21
              + q20*c02 + q21*c12 + q22*c22;
    float kk = trP / ny2;
    float r00=kk*q00, r01=kk*q01, r02=kk*q02;
    float r10=kk*q10, r11=kk*q11, r12=kk*q12;
    float r20=kk*q20, r21=kk*q21, r22=kk*q22;

    // ---- pass 2: per-joint error (targ re-read from LDS, pred from regs) ----
    float errsum = 0.0f;
    #pragma unroll
    for (int k = 0; k < KMAX; ++k) {
        const int n = 2 * k + sub;
        if (n < NPTS) {
            const int o = base + 3 * n;
            float xa = lx[o+0], xb = lx[o+1], xc = lx[o+2];
            float u = py0[k] - muy0, v = py1[k] - muy1, x2 = py2[k] - muy2;
            float z0 = fmaf(u, r00, fmaf(v, r10, fmaf(x2, r20, mux0))) - xa;
            float z1 = fmaf(u, r01, fmaf(v, r11, fmaf(x2, r21, mux1))) - xb;
            float z2 = fmaf(u, r02, fmaf(v, r12, fmaf(x2, r22, mux2))) - xc;
            errsum += sqrtf(fmaf(z0, z0, fmaf(z1, z1, z2*z2)));
        }
    }

    // ---- full-wave reduce (covers all 32 batches) -> one store per block ----
    #pragma unroll
    for (int off = 32; off > 0; off >>= 1) errsum += __shfl_down(errsum, off, 64);
    if (lane == 0) ws[blockIdx.x] = errsum;
}

// single block: reduce the per-block partials, write the final mean
__global__ __launch_bounds__(256)
void pa_reduce(const float* __restrict__ ws, float* __restrict__ out,
               int nblk, float inv_total)
{
    __shared__ float sw[4];
    float s = 0.0f;
    const float4* w4 = (const float4*)ws;
    const int n4 = nblk >> 2;                  // nblk divisible by 4
    for (int i = threadIdx.x; i < n4; i += 256) {
        float4 v = w4[i];
        s += (v.x + v.y) + (v.z + v.w);
    }
    #pragma unroll
    for (int off = 32; off > 0; off >>= 1) s += __shfl_down(s, off, 64);
    if ((threadIdx.x & 63) == 0) sw[threadIdx.x >> 6] = s;
    __syncthreads();
    if (threadIdx.x == 0)
        out[0] = (sw[0] + sw[1] + sw[2] + sw[3]) * inv_total;
}

extern "C" void kernel_launch(void* const* d_in, const int* in_sizes, int n_in,
                              void* d_out, int out_size, void* d_ws, size_t ws_size,
                              hipStream_t stream)
{
    const float* pred = (const float*)d_in[0];   // pred_kp3d   [B,21,3] f32
    const float* targ = (const float*)d_in[1];   // target_kp3d [B,21,3] f32
    float* out = (float*)d_out;
    float* ws  = (float*)d_ws;

    int B = in_sizes[0] / FLB;                   // 262144 (divisible by BPW)
    int grid = (B + BPW - 1) / BPW;              // 8192 blocks, 1 wave each
    float inv_total = 1.0f / ((float)B * (float)NPTS);

    pa_mpjpe<<<grid, THREADS, 0, stream>>>(pred, targ, ws, B);
    pa_reduce<<<1, 256, 0, stream>>>(ws, out, grid, inv_total);
}